// Round 1
// baseline (394.028 us; speedup 1.0000x reference)
//
#include <hip/hip_runtime.h>

// Problem constants
#define DIMC 192
#define HID  48          // DIM / RED
#define HW   65536       // 256*256
#define WIDTH 256
#define NPLANE 768       // B * DIM

// ---------------------------------------------------------------------------
// Kernel 1: per-(b,c) mean over the 256x256 plane.
// 768 blocks x 1024 threads; each thread sums 16 float4 (64 floats), then
// wave shuffle-reduce + LDS cross-wave reduce.
// ---------------------------------------------------------------------------
__global__ __launch_bounds__(1024) void k_pool(const float* __restrict__ x,
                                               float* __restrict__ pooled) {
    const int plane = blockIdx.x;  // 0..767
    const float4* p = (const float4*)(x + (size_t)plane * HW);
    const int t = threadIdx.x;
    float s = 0.f;
#pragma unroll
    for (int k = 0; k < 16; ++k) {
        float4 v = p[k * 1024 + t];
        s += (v.x + v.y) + (v.z + v.w);
    }
    // wave (64-lane) reduce
#pragma unroll
    for (int off = 32; off > 0; off >>= 1) s += __shfl_down(s, off, 64);
    __shared__ float wsum[16];
    const int wave = t >> 6, lane = t & 63;
    if (lane == 0) wsum[wave] = s;
    __syncthreads();
    if (t == 0) {
        float tot = 0.f;
#pragma unroll
        for (int i = 0; i < 16; ++i) tot += wsum[i];
        pooled[plane] = tot * (1.0f / 65536.0f);
    }
}

// ---------------------------------------------------------------------------
// Kernel 2: dynamic weight generation. One block per sample (4 blocks, 256 thr).
//   t = relu(BN(pooled @ w1^T)); taps = t @ w2^T + b2, keep only the 4
//   unmasked taps (ky,kx) in {(0,0),(0,1),(0,2),(1,0)} -> float4 per (b,c).
// ---------------------------------------------------------------------------
__global__ __launch_bounds__(256) void k_weights(
    const float* __restrict__ pooled,   // [4,192]
    const float* __restrict__ w1,       // [48,192]
    const float* __restrict__ gamma,
    const float* __restrict__ beta,
    const float* __restrict__ rmean,
    const float* __restrict__ rvar,
    const float* __restrict__ w2,       // [1728,48]
    const float* __restrict__ b2,       // [1728]
    float* __restrict__ w4)             // [4,192,4]
{
    const int b = blockIdx.x;
    const int tid = threadIdx.x;
    __shared__ float P[DIMC];
    __shared__ float T[HID];
    if (tid < DIMC) P[tid] = pooled[b * DIMC + tid];
    __syncthreads();
    if (tid < HID) {
        const float* wr = w1 + tid * DIMC;
        float acc = 0.f;
        for (int d = 0; d < DIMC; ++d) acc += P[d] * wr[d];
        const float inv = 1.0f / sqrtf(rvar[tid] + 1e-5f);
        float v = gamma[tid] * (acc - rmean[tid]) * inv + beta[tid];
        T[tid] = v > 0.f ? v : 0.f;
    }
    __syncthreads();
    // 192 channels * 4 taps = 768 outputs per sample; 3 per thread
    for (int idx = tid; idx < DIMC * 4; idx += 256) {
        const int c = idx >> 2, tap = idx & 3;
        const int o = c * 9 + tap;           // taps 0..3 of the 3x3 kernel
        const float* wr = w2 + o * HID;
        float acc = b2[o];
        for (int j = 0; j < HID; ++j) acc += T[j] * wr[j];
        w4[b * DIMC * 4 + idx] = acc;
    }
}

// ---------------------------------------------------------------------------
// Kernel 3: 4-tap masked depthwise conv.
//   out[y][x] = w00*X[y-1][x-1] + w01*X[y-1][x] + w02*X[y-1][x+1]
//             + w10*X[y  ][x-1] + bias[c]
// One wave per group of 8 consecutive rows of one plane; 64 lanes x float4
// cover one 256-px row exactly. Column halos via wave shuffles; row halo is
// the rolling register from the previous iteration (x read ~1.125x).
// Grid: 768 planes * 8 row-tiles = 6144 blocks; block = 4 waves (8 rows each).
// ---------------------------------------------------------------------------
__global__ __launch_bounds__(256) void k_conv(const float* __restrict__ x,
                                              const float4* __restrict__ w4,
                                              const float* __restrict__ bias,
                                              float* __restrict__ out) {
    const int plane = blockIdx.x >> 3;          // 0..767 (= b*192 + c)
    const int c = plane % DIMC;
    const int wave = threadIdx.x >> 6;
    const int lane = threadIdx.x & 63;
    const int y0 = ((blockIdx.x & 7) << 5) + (wave << 3);
    const float4 wt = w4[plane];                // {w00, w01, w02, w10}
    const float bs = bias[c];
    const float4* xp = (const float4*)(x + (size_t)plane * HW);
    float4* op = (float4*)(out + (size_t)plane * HW);

    float4 a;                                   // row y-1
    if (y0 == 0) a = make_float4(0.f, 0.f, 0.f, 0.f);
    else         a = xp[(y0 - 1) * 64 + lane];

#pragma unroll
    for (int r = 0; r < 8; ++r) {
        const int y = y0 + r;
        float4 bb = xp[y * 64 + lane];          // row y
        float leftA  = __shfl_up(a.w, 1, 64);   if (lane == 0)  leftA  = 0.f;
        float rightA = __shfl_down(a.x, 1, 64); if (lane == 63) rightA = 0.f;
        float leftB  = __shfl_up(bb.w, 1, 64);  if (lane == 0)  leftB  = 0.f;
        float4 o;
        o.x = wt.x * leftA + wt.y * a.x + wt.z * a.y   + wt.w * leftB + bs;
        o.y = wt.x * a.x   + wt.y * a.y + wt.z * a.z   + wt.w * bb.x  + bs;
        o.z = wt.x * a.y   + wt.y * a.z + wt.z * a.w   + wt.w * bb.y  + bs;
        o.w = wt.x * a.z   + wt.y * a.w + wt.z * rightA + wt.w * bb.z + bs;
        op[y * 64 + lane] = o;
        a = bb;                                 // roll: row y becomes row y-1
    }
}

// ---------------------------------------------------------------------------
extern "C" void kernel_launch(void* const* d_in, const int* in_sizes, int n_in,
                              void* d_out, int out_size, void* d_ws, size_t ws_size,
                              hipStream_t stream) {
    const float* x     = (const float*)d_in[0];
    const float* w1    = (const float*)d_in[1];
    const float* gamma = (const float*)d_in[2];
    const float* beta  = (const float*)d_in[3];
    const float* rmean = (const float*)d_in[4];
    const float* rvar  = (const float*)d_in[5];
    const float* w2    = (const float*)d_in[6];
    const float* b2    = (const float*)d_in[7];
    const float* bias  = (const float*)d_in[8];
    float* out = (float*)d_out;

    float* pooled = (float*)d_ws;        // 768 floats
    float* w4     = pooled + NPLANE;     // 768 float4 = 3072 floats (16B aligned)

    k_pool<<<NPLANE, 1024, 0, stream>>>(x, pooled);
    k_weights<<<4, 256, 0, stream>>>(pooled, w1, gamma, beta, rmean, rvar, w2, b2, w4);
    k_conv<<<NPLANE * 8, 256, 0, stream>>>(x, (const float4*)w4, bias, out);
}